// Round 12
// baseline (747.196 us; speedup 1.0000x reference)
//
#include <hip/hip_runtime.h>
#include <hip/hip_bf16.h>

#define B_ 4
#define H_ 16
#define S_ 2048
#define D_ 128
#define NEGV -1000000000.0f
#define LOG2E 1.44269504f
#define THR 9.0f

typedef _Float16 f16;
typedef __attribute__((ext_vector_type(8))) _Float16 f16x8;
typedef __attribute__((ext_vector_type(4))) _Float16 f16x4v;
typedef __attribute__((ext_vector_type(2))) __fp16 fp16x2_b;
typedef __attribute__((ext_vector_type(4))) float f32x4;

__device__ inline unsigned int pack2h(float lo, float hi){
  union { f16 h[2]; unsigned int u; } cv;
  cv.h[0] = (f16)lo; cv.h[1] = (f16)hi;
  return cv.u;
}
__device__ inline unsigned short f2h16(float x){
  union { f16 h; unsigned short u; } cv; cv.h = (f16)x; return cv.u;
}
__device__ inline unsigned int pkrtz(float a, float b){
  union { fp16x2_b h; unsigned int u; } cv;
  cv.h = __builtin_amdgcn_cvt_pkrtz(a, b);
  return cv.u;
}
__device__ inline void async16(void* l, const void* g){
  __builtin_amdgcn_global_load_lds(
      (const __attribute__((address_space(1))) unsigned int*)g,
      (__attribute__((address_space(3))) unsigned int*)l, 16, 0, 0);
}

// ws layout (MID): [mask bits 2MB][K f16 tiles 32MB][Vt f16 tiles 32MB]
constexpr size_t MBW     = (size_t)B_*S_*(S_/32);       // 524288 words
constexpr size_t KBYTES  = (size_t)B_*H_*S_*D_*2;       // 33554432
constexpr size_t WS_MID  = MBW*4 + 2*KBYTES;            // 69206016

// ============ prepass (KBLK=32): K tiles [32][256B] swizzled ((kr&7)<<4),
//              Vt tiles [128 d][64B] swizzled ((d&3)<<4), mask->bits.
//              bid = bh*64 + kb32  (4096 blocks)
__global__ __launch_bounds__(256)
void prepass(const float* __restrict__ K, const float* __restrict__ V,
             const int* __restrict__ mask, unsigned int* __restrict__ mbits,
             char* __restrict__ wsK, char* __restrict__ wsV)
{
  __shared__ char Vim[8192];
  int bid = blockIdx.x, tid = threadIdx.x;
  size_t base = (size_t)bid * (32*128);
  const float* kp = K + base;
  char* ok = wsK + (size_t)bid*8192;
  #pragma unroll
  for (int j = 0; j < 4; ++j){
    int f = tid + j*256; int kr = f>>5, c = f&31;   // kr 0..31, c 0..31
    float4 v = *(const float4*)(kp + kr*128 + c*4);
    unsigned int lo = pack2h(v.x, v.y), hi = pack2h(v.z, v.w);
    int off = kr*256 + ((c*8) ^ ((kr&7)<<4));
    *(uint2*)(ok + off) = make_uint2(lo, hi);
  }
  const float* vp = V + base;
  #pragma unroll
  for (int j = 0; j < 4; ++j){
    int f = tid + j*256; int k = f>>5, c = f&31;    // k 0..31
    float4 v = *(const float4*)(vp + k*128 + c*4);
    float e[4] = {v.x, v.y, v.z, v.w};
    #pragma unroll
    for (int u = 0; u < 4; ++u){
      int d = c*4 + u;
      *(unsigned short*)(Vim + d*64 + ((2*k) ^ ((d&3)<<4))) = f2h16(e[u]);
    }
  }
  __syncthreads();
  char* ov = wsV + (size_t)bid*8192;
  #pragma unroll
  for (int j = 0; j < 2; ++j)
    *(uint4*)(ov + tid*16 + j*4096) = *(const uint4*)(Vim + tid*16 + j*4096);
  if (tid < 128){
    size_t wdx = (size_t)bid*128 + tid;
    const int* p = mask + wdx*32;
    unsigned int o = 0;
    #pragma unroll
    for (int i = 0; i < 32; i += 4){
      int4 m4 = *(const int4*)(p + i);
      o |= (m4.x ? 1u<<i : 0u) | (m4.y ? 1u<<(i+1) : 0u)
         | (m4.z ? 1u<<(i+2) : 0u) | (m4.w ? 1u<<(i+3) : 0u);
    }
    mbits[wdx] = o;
  }
}

// ============ fast attention: KBLK=32, 4 waves x 32 q-rows, 36KB LDS -> 4 blocks/CU
__global__ __launch_bounds__(256, 4)
void attn_fast(const float* __restrict__ Q,
               const unsigned int* __restrict__ mbits,
               const char* __restrict__ wsK, const char* __restrict__ wsV,
               float* __restrict__ out)
{
  __shared__ char KB[2][8192];      // K tile: 32 rows x 256B, swz (kr&7)<<4
  __shared__ char VB[2][8192];      // Vt tile: 128 d x 64B, swz (d&3)<<4
  __shared__ char PL[4096];         // 64 q-rows x 64B, swz (r&3)<<4

  int bid = blockIdx.x;
  int wg = (bid & 7) * 128 + (bid >> 3);   // 1024 wgs, bijective XCD swizzle
  int bh = wg >> 4, qb = wg & 15;
  int b  = bh >> 4;
  int tid = threadIdx.x;
  int w = tid >> 6, lane = tid & 63;
  int g = lane >> 4, r = lane & 15;
  int swk = (r & 7) << 4;                  // K-tile swizzle (256B rows)
  int swp = (r & 3) << 4;                  // Vt/PL swizzle (64B rows)
  int sh4 = g * 4;
  size_t base = (size_t)bh * (S_*D_);
  int qg0 = qb*128 + w*32 + r;
  int qg1 = qg0 + 16;
  char* prow = PL + (w*16 + r)*64;

  // precomputed offsets (loop-invariant)
  int xq0 = (g*16) ^ swk;                  // K d-chunk reads (dc*64 strides added)
  int xq1 = (64 + g*16) ^ swk;
  int xq2 = (128 + g*16) ^ swk;
  int xq3 = (192 + g*16) ^ swk;
  int xpt0 = (g*8) ^ swp;                  // PL writes, t=0
  int xpt1 = (32 + g*8) ^ swp;             // t=1
  int xqp = (g*16) ^ swp;                  // PL read / Vt read

  // Q fragments (B-operand of swapped QK^T), 2 q-rows per lane
  f16x8 qf[2][4];
  #pragma unroll
  for (int u = 0; u < 2; ++u){
    const float* qp = Q + base + (size_t)(u ? qg1 : qg0) * D_;
    #pragma unroll
    for (int dc = 0; dc < 4; ++dc){
      float4 a = *(const float4*)(qp + dc*32 + g*8);
      float4 c = *(const float4*)(qp + dc*32 + g*8 + 4);
      f16x8 q8;
      q8[0]=(f16)a.x; q8[1]=(f16)a.y; q8[2]=(f16)a.z; q8[3]=(f16)a.w;
      q8[4]=(f16)c.x; q8[5]=(f16)c.y; q8[6]=(f16)c.z; q8[7]=(f16)c.w;
      qf[u][dc] = q8;
    }
  }

  const char* gK = wsK + (size_t)(bh*64)*8192 + tid*16;
  const char* gV = wsV + (size_t)(bh*64)*8192 + tid*16;
  const unsigned int* mr0 = mbits + ((size_t)b*S_ + qg0)*64;
  const unsigned int* mr1 = mbits + ((size_t)b*S_ + qg1)*64;

  // prologue: masks(0) + stage tile 0 into buffer 0  (FIFO: 2 mask + 4 async)
  unsigned int mwc0 = mr0[0], mwc1 = mr1[0];
  #pragma unroll
  for (int j = 0; j < 2; ++j){
    async16(&KB[0][tid*16 + j*4096], gK + j*4096);
    async16(&VB[0][tid*16 + j*4096], gV + j*4096);
  }

  float m0 = -3.0e38f, m1 = -3.0e38f;
  f32x4 acc[2][8];
  f32x4 accl[2];
  f32x4 z4 = (f32x4){0.f,0.f,0.f,0.f};
  #pragma unroll
  for (int u = 0; u < 2; ++u){
    accl[u] = z4;
    #pragma unroll
    for (int i = 0; i < 8; ++i) acc[u][i] = z4;
  }
  f16x8 ones;
  #pragma unroll
  for (int i = 0; i < 8; ++i) ones[i] = (f16)1.0f;

  unsigned int mwn0 = 0, mwn1 = 0;

  for (int kb = 0; kb < 64; ++kb){
    int cur = kb & 1;
    if (kb < 63){
      mwn0 = mr0[kb+1]; mwn1 = mr1[kb+1];
      const char* gk = gK + (size_t)(kb+1)*8192;
      const char* gv = gV + (size_t)(kb+1)*8192;
      #pragma unroll
      for (int j = 0; j < 2; ++j){
        async16(&KB[cur^1][tid*16 + j*4096], gk + j*4096);
        async16(&VB[cur^1][tid*16 + j*4096], gv + j*4096);
      }
      asm volatile("s_waitcnt vmcnt(6)" ::: "memory");
    } else {
      asm volatile("s_waitcnt vmcnt(0)" ::: "memory");
    }
    __builtin_amdgcn_s_barrier();

    const char* kbuf = KB[cur];
    const char* vbuf = VB[cur];

    // ---- QK^T (swapped), C=0 init via z4 on dc==0 ----
    f32x4 st[2][2];
    __builtin_amdgcn_s_setprio(1);
    #pragma unroll
    for (int t = 0; t < 2; ++t){
      const char* kr_ = kbuf + (t*16 + r)*256;
      f16x8 kf = *(const f16x8*)(kr_ + xq0);
      st[0][t] = __builtin_amdgcn_mfma_f32_16x16x32_f16(kf, qf[0][0], z4, 0, 0, 0);
      st[1][t] = __builtin_amdgcn_mfma_f32_16x16x32_f16(kf, qf[1][0], z4, 0, 0, 0);
      kf = *(const f16x8*)(kr_ + xq1);
      st[0][t] = __builtin_amdgcn_mfma_f32_16x16x32_f16(kf, qf[0][1], st[0][t], 0, 0, 0);
      st[1][t] = __builtin_amdgcn_mfma_f32_16x16x32_f16(kf, qf[1][1], st[1][t], 0, 0, 0);
      kf = *(const f16x8*)(kr_ + xq2);
      st[0][t] = __builtin_amdgcn_mfma_f32_16x16x32_f16(kf, qf[0][2], st[0][t], 0, 0, 0);
      st[1][t] = __builtin_amdgcn_mfma_f32_16x16x32_f16(kf, qf[1][2], st[1][t], 0, 0, 0);
      kf = *(const f16x8*)(kr_ + xq3);
      st[0][t] = __builtin_amdgcn_mfma_f32_16x16x32_f16(kf, qf[0][3], st[0][t], 0, 0, 0);
      st[1][t] = __builtin_amdgcn_mfma_f32_16x16x32_f16(kf, qf[1][3], st[1][t], 0, 0, 0);
    }
    __builtin_amdgcn_s_setprio(0);

    // ---- mask (u32: k = t*16 + g*4 + i) ----
    #pragma unroll
    for (int u = 0; u < 2; ++u){
      unsigned int mw = u ? mwc1 : mwc0;
      unsigned int tv0 = mw >> sh4;
      unsigned int tv1 = mw >> (16 + sh4);
      #pragma unroll
      for (int i = 0; i < 4; ++i){
        if (!((tv0 >> i) & 1u)) st[u][0][i] = NEGV;
        if (!((tv1 >> i) & 1u)) st[u][1][i] = NEGV;
      }
    }

    // ---- online softmax (defer-rescale) ----
    float pmax0 = fmaxf(fmaxf(fmaxf(st[0][0][0], st[0][0][1]), fmaxf(st[0][0][2], st[0][0][3])),
                        fmaxf(fmaxf(st[0][1][0], st[0][1][1]), fmaxf(st[0][1][2], st[0][1][3])));
    float pmax1 = fmaxf(fmaxf(fmaxf(st[1][0][0], st[1][0][1]), fmaxf(st[1][0][2], st[1][0][3])),
                        fmaxf(fmaxf(st[1][1][0], st[1][1][1]), fmaxf(st[1][1][2], st[1][1][3])));
    pmax0 = fmaxf(pmax0, __shfl_xor(pmax0, 16));
    pmax0 = fmaxf(pmax0, __shfl_xor(pmax0, 32));
    pmax1 = fmaxf(pmax1, __shfl_xor(pmax1, 16));
    pmax1 = fmaxf(pmax1, __shfl_xor(pmax1, 32));

    bool need = (pmax0 > m0 + THR) || (pmax1 > m1 + THR);
    if (__ballot(need)){
      float n0 = fmaxf(m0, pmax0), n1 = fmaxf(m1, pmax1);
      float cr0 = __builtin_amdgcn_exp2f((m0 - n0) * LOG2E);
      float cr1 = __builtin_amdgcn_exp2f((m1 - n1) * LOG2E);
      float cj0[4], cj1[4];
      #pragma unroll
      for (int j = 0; j < 4; ++j){
        cj0[j] = __shfl(cr0, sh4 + j);
        cj1[j] = __shfl(cr1, sh4 + j);
      }
      #pragma unroll
      for (int dt = 0; dt < 8; ++dt)
        #pragma unroll
        for (int j = 0; j < 4; ++j){
          acc[0][dt][j] *= cj0[j];
          acc[1][dt][j] *= cj1[j];
        }
      #pragma unroll
      for (int j = 0; j < 4; ++j){
        accl[0][j] *= cj0[j];
        accl[1][j] *= cj1[j];
      }
      m0 = n0; m1 = n1;
    }
    float mL0 = m0 * LOG2E, mL1 = m1 * LOG2E;

    // ---- P = exp2(s*log2e - mL) -> PL -> A-fragments ----
    f16x8 pf[2];
    #pragma unroll
    for (int u = 0; u < 2; ++u){
      float mL = u ? mL1 : mL0;
      {
        float p0 = __builtin_amdgcn_exp2f(__builtin_fmaf(st[u][0][0], LOG2E, -mL));
        float p1 = __builtin_amdgcn_exp2f(__builtin_fmaf(st[u][0][1], LOG2E, -mL));
        float p2 = __builtin_amdgcn_exp2f(__builtin_fmaf(st[u][0][2], LOG2E, -mL));
        float p3 = __builtin_amdgcn_exp2f(__builtin_fmaf(st[u][0][3], LOG2E, -mL));
        *(uint2*)(prow + xpt0) = make_uint2(pkrtz(p0,p1), pkrtz(p2,p3));
        p0 = __builtin_amdgcn_exp2f(__builtin_fmaf(st[u][1][0], LOG2E, -mL));
        p1 = __builtin_amdgcn_exp2f(__builtin_fmaf(st[u][1][1], LOG2E, -mL));
        p2 = __builtin_amdgcn_exp2f(__builtin_fmaf(st[u][1][2], LOG2E, -mL));
        p3 = __builtin_amdgcn_exp2f(__builtin_fmaf(st[u][1][3], LOG2E, -mL));
        *(uint2*)(prow + xpt1) = make_uint2(pkrtz(p0,p1), pkrtz(p2,p3));
      }
      pf[u] = *(const f16x8*)(prow + xqp);
    }

    // ---- row sums via ones-MFMA ----
    accl[0] = __builtin_amdgcn_mfma_f32_16x16x32_f16(pf[0], ones, accl[0], 0, 0, 0);
    accl[1] = __builtin_amdgcn_mfma_f32_16x16x32_f16(pf[1], ones, accl[1], 0, 0, 0);

    // ---- PV: shared V fragments serve both q-halves ----
    __builtin_amdgcn_s_setprio(1);
    #pragma unroll
    for (int dt = 0; dt < 8; ++dt){
      f16x8 v0 = *(const f16x8*)(vbuf + (dt*16 + r)*64 + xqp);
      acc[0][dt] = __builtin_amdgcn_mfma_f32_16x16x32_f16(pf[0], v0, acc[0][dt], 0, 0, 0);
      acc[1][dt] = __builtin_amdgcn_mfma_f32_16x16x32_f16(pf[1], v0, acc[1][dt], 0, 0, 0);
    }
    __builtin_amdgcn_s_setprio(0);

    mwc0 = mwn0; mwc1 = mwn1;
    __builtin_amdgcn_s_barrier();
  }

  // ---- epilogue: normalize by ones-MFMA row sums, store fp32 ----
  #pragma unroll
  for (int u = 0; u < 2; ++u){
    float inv[4];
    #pragma unroll
    for (int j = 0; j < 4; ++j) inv[j] = 1.f / accl[u][j];
    size_t ob = base + (size_t)(qb*128 + w*32 + u*16) * D_;
    #pragma unroll
    for (int dt = 0; dt < 8; ++dt){
      int d = dt*16 + r;
      #pragma unroll
      for (int j = 0; j < 4; ++j)
        out[ob + (size_t)(sh4 + j)*D_ + d] = acc[u][dt][j] * inv[j];
    }
  }
}

// ============ fallback (round-2 proven, direct mask, no ws) ============
constexpr int VTS = 68;
constexpr int PSS = 72;

__global__ __launch_bounds__(256)
void attn_fwd(const float* __restrict__ Q, const float* __restrict__ K,
              const float* __restrict__ V, const int* __restrict__ mask,
              float* __restrict__ out)
{
  __shared__ unsigned short Klds[64 * D_];
  __shared__ unsigned short Vt[D_ * VTS];
  __shared__ unsigned short Plds[4 * 16 * PSS];

  int bid = blockIdx.x;
  int wg = (bid & 7) * 256 + (bid >> 3);
  int bh = wg >> 5, qb = wg & 31;
  int b  = bh >> 4;
  int tid = threadIdx.x;
  int w = tid >> 6, lane = tid & 63;
  int g = lane >> 4, r = lane & 15;
  size_t base = (size_t)bh * S_ * D_;
  int qg = qb * 64 + w * 16 + r;

  f16x8 qf[4];
  {
    const float* qp = Q + base + (size_t)qg * D_;
    #pragma unroll
    for (int dc = 0; dc < 4; ++dc){
      float4 a = *reinterpret_cast<const float4*>(qp + dc*32 + g*8);
      float4 c = *reinterpret_cast<const float4*>(qp + dc*32 + g*8 + 4);
      f16x8 q8;
      q8[0]=(f16)a.x; q8[1]=(f16)a.y; q8[2]=(f16)a.z; q8[3]=(f16)a.w;
      q8[4]=(f16)c.x; q8[5]=(f16)c.y; q8[6]=(f16)c.z; q8[7]=(f16)c.w;
      qf[dc] = q8;
    }
  }

  float mrun = -3.0e38f, lrun = 0.f;
  f32x4 acc[8];
  #pragma unroll
  for (int i = 0; i < 8; ++i) acc[i] = (f32x4){0.f,0.f,0.f,0.f};

  for (int kb = 0; kb < S_/64; ++kb){
    const float* kp = K + base + (size_t)(kb*64) * D_;
    #pragma unroll
    for (int i = 0; i < 8; ++i){
      int f = tid + i*256;
      int kr = f >> 5, c = f & 31;
      float4 v = *reinterpret_cast<const float4*>(kp + kr*D_ + c*4);
      unsigned int lo = pack2h(v.x, v.y), hi = pack2h(v.z, v.w);
      int off = (kr*256 + c*8) ^ ((kr & 7) << 4);
      *reinterpret_cast<uint2*>(reinterpret_cast<char*>(Klds) + off) = make_uint2(lo, hi);
    }
    const float* vp = V + base + (size_t)(kb*64) * D_;
    #pragma unroll
    for (int i = 0; i < 4; ++i){
      int f = tid + i*256;
      int p = f >> 5, c = f & 31;
      float4 v0 = *reinterpret_cast<const float4*>(vp + (size_t)(2*p)*D_ + c*4);
      float4 v1 = *reinterpret_cast<const float4*>(vp + (size_t)(2*p+1)*D_ + c*4);
      float e0[4] = {v0.x, v0.y, v0.z, v0.w};
      float e1[4] = {v1.x, v1.y, v1.z, v1.w};
      #pragma unroll
      for (int j = 0; j < 4; ++j){
        int d = c*4 + j;
        *reinterpret_cast<unsigned int*>(reinterpret_cast<char*>(Vt) + (d*VTS + 2*p)*2)
            = pack2h(e0[j], e1[j]);
      }
    }
    __syncthreads();

    f32x4 st[4];
    #pragma unroll
    for (int t = 0; t < 4; ++t){
      f32x4 s = (f32x4){0.f,0.f,0.f,0.f};
      int row = t*16 + r;
      #pragma unroll
      for (int dc = 0; dc < 4; ++dc){
        int off = row*256 + ((dc*64 + g*16) ^ ((row & 7) << 4));
        f16x8 kf = *reinterpret_cast<const f16x8*>(reinterpret_cast<const char*>(Klds) + off);
        s = __builtin_amdgcn_mfma_f32_16x16x32_f16(kf, qf[dc], s, 0, 0, 0);
      }
      st[t] = s;
    }

    #pragma unroll
    for (int t = 0; t < 4; ++t){
      int4 m4 = *reinterpret_cast<const int4*>(
          mask + ((size_t)b * S_ + qg) * S_ + kb*64 + t*16 + g*4);
      if (!m4.x) st[t][0] = NEGV;
      if (!m4.y) st[t][1] = NEGV;
      if (!m4.z) st[t][2] = NEGV;
      if (!m4.w) st[t][3] = NEGV;
    }

    float pmax = st[0][0];
    #pragma unroll
    for (int t = 0; t < 4; ++t)
      #pragma unroll
      for (int i = 0; i < 4; ++i) pmax = fmaxf(pmax, st[t][i]);
    pmax = fmaxf(pmax, __shfl_xor(pmax, 16));
    pmax = fmaxf(pmax, __shfl_xor(pmax, 32));
    float mnew = fmaxf(mrun, pmax);
    float corr = __builtin_amdgcn_exp2f((mrun - mnew) * LOG2E);
    float psum = 0.f;
    char* prow = reinterpret_cast<char*>(Plds) + (size_t)(w*16 + r)*PSS*2;
    #pragma unroll
    for (int t = 0; t < 4; ++t){
      float p0 = __builtin_amdgcn_exp2f((st[t][0]-mnew)*LOG2E);
      float p1 = __builtin_amdgcn_exp2f((st[t][1]-mnew)*LOG2E);
      float p2 = __builtin_amdgcn_exp2f((st[t][2]-mnew)*LOG2E);
      float p3 = __builtin_amdgcn_exp2f((st[t][3]-mnew)*LOG2E);
      psum += (p0+p1)+(p2+p3);
      char* pb = prow + (t*16 + g*4)*2;
      *reinterpret_cast<unsigned int*>(pb)     = pack2h(p0, p1);
      *reinterpret_cast<unsigned int*>(pb + 4) = pack2h(p2, p3);
    }
    psum += __shfl_xor(psum, 16);
    psum += __shfl_xor(psum, 32);
    lrun = lrun * corr + psum;
    mrun = mnew;
    float cq0 = __shfl(corr, g*4 + 0);
    float cq1 = __shfl(corr, g*4 + 1);
    float cq2 = __shfl(corr, g*4 + 2);
    float cq3 = __shfl(corr, g*4 + 3);
    #pragma unroll
    for (int dt = 0; dt < 8; ++dt){
      acc[dt][0] *= cq0; acc[dt][1] *= cq1; acc[dt][2] *= cq2; acc[dt][3] *= cq3;
    }

    f16x8 pf0 = *reinterpret_cast<const f16x8*>(prow + g*16);
    f16x8 pf1 = *reinterpret_cast<const f16x8*>(prow + 64 + g*16);
    #pragma unroll
    for (int dt = 0; dt < 8; ++dt){
      int vo = (dt*16 + r)*VTS*2 + g*16;
      const char* vb = reinterpret_cast<const char*>(Vt);
      union { f16x8 v; f16x4v h[2]; } uv0, uv1;
      uv0.h[0] = *reinterpret_cast<const f16x4v*>(vb + vo);
      uv0.h[1] = *reinterpret_cast<const f16x4v*>(vb + vo + 8);
      acc[dt] = __builtin_amdgcn_mfma_f32_16x16x32_f16(pf0, uv0.v, acc[dt], 0, 0, 0);
      uv1.h[0] = *reinterpret_cast<const f16x4v*>(vb + vo + 64);
      uv1.h[1] = *reinterpret_cast<const f16x4v*>(vb + vo + 72);
      acc[dt] = __builtin_amdgcn_mfma_f32_16x16x32_f16(pf1, uv1.v, acc[dt], 0, 0, 0);
    }
    __syncthreads();
  }

  float l0 = __shfl(lrun, g*4 + 0);
  float l1 = __shfl(lrun, g*4 + 1);
  float l2 = __shfl(lrun, g*4 + 2);
  float l3 = __shfl(lrun, g*4 + 3);
  float i0 = 1.f/l0, i1 = 1.f/l1, i2 = 1.f/l2, i3 = 1.f/l3;
  size_t obase = base + (size_t)(qb*64 + w*16) * D_;
  #pragma unroll
  for (int dt = 0; dt < 8; ++dt){
    int d = dt*16 + r;
    out[obase + (size_t)(g*4 + 0)*D_ + d] = acc[dt][0]*i0;
    out[obase + (size_t)(g*4 + 1)*D_ + d] = acc[dt][1]*i1;
    out[obase + (size_t)(g*4 + 2)*D_ + d] = acc[dt][2]*i2;
    out[obase + (size_t)(g*4 + 3)*D_ + d] = acc[dt][3]*i3;
  }
}

extern "C" void kernel_launch(void* const* d_in, const int* in_sizes, int n_in,
                              void* d_out, int out_size, void* d_ws, size_t ws_size,
                              hipStream_t stream) {
  const float* Q = (const float*)d_in[0];
  const float* K = (const float*)d_in[1];
  const float* V = (const float*)d_in[2];
  const int* mask = (const int*)d_in[3];
  float* out = (float*)d_out;

  if (ws_size >= WS_MID){
    unsigned int* mbits = (unsigned int*)d_ws;
    char* wsK = (char*)d_ws + MBW*4;
    char* wsV = wsK + KBYTES;
    prepass<<<dim3(4096), dim3(256), 0, stream>>>(K, V, mask, mbits, wsK, wsV);
    attn_fast<<<dim3(1024), dim3(256), 0, stream>>>(Q, mbits, wsK, wsV, out);
  } else {
    attn_fwd<<<dim3(2048), dim3(256), 0, stream>>>(Q, K, V, mask, out);
  }
}

// Round 13
// 292.226 us; speedup vs baseline: 2.5569x; 2.5569x over previous
//
#include <hip/hip_runtime.h>
#include <hip/hip_bf16.h>

#define B_ 4
#define H_ 16
#define S_ 2048
#define D_ 128
#define NEGV -1000000000.0f
#define LOG2E 1.44269504f
#define THR 9.0f

typedef _Float16 f16;
typedef __attribute__((ext_vector_type(8))) _Float16 f16x8;
typedef __attribute__((ext_vector_type(4))) _Float16 f16x4v;
typedef __attribute__((ext_vector_type(2))) __fp16 fp16x2_b;
typedef __attribute__((ext_vector_type(4))) float f32x4;

__device__ inline unsigned int pack2h(float lo, float hi){
  union { f16 h[2]; unsigned int u; } cv;
  cv.h[0] = (f16)lo; cv.h[1] = (f16)hi;
  return cv.u;
}
__device__ inline unsigned short f2h16(float x){
  union { f16 h; unsigned short u; } cv; cv.h = (f16)x; return cv.u;
}
__device__ inline unsigned int pkrtz(float a, float b){
  union { fp16x2_b h; unsigned int u; } cv;
  cv.h = __builtin_amdgcn_cvt_pkrtz(a, b);
  return cv.u;
}
__device__ inline void async16(void* l, const void* g){
  __builtin_amdgcn_global_load_lds(
      (const __attribute__((address_space(1))) unsigned int*)g,
      (__attribute__((address_space(3))) unsigned int*)l, 16, 0, 0);
}

// ws layout (MID): [mask bits 2MB][K f16 tiles 32MB][Vt f16 tiles 32MB]
constexpr size_t MBW     = (size_t)B_*S_*(S_/32);       // 524288 words
constexpr size_t KBYTES  = (size_t)B_*H_*S_*D_*2;       // 33554432
constexpr size_t WS_MID  = MBW*4 + 2*KBYTES;            // 69206016

// ============ prepass (KBLK=32): K tiles [32][256B] swizzled ((kr&7)<<4),
//              Vt tiles [128 d][64B] swizzled ((d&3)<<4), mask->bits.
//              bid = bh*64 + kb32  (4096 blocks)
__global__ __launch_bounds__(256)
void prepass(const float* __restrict__ K, const float* __restrict__ V,
             const int* __restrict__ mask, unsigned int* __restrict__ mbits,
             char* __restrict__ wsK, char* __restrict__ wsV)
{
  __shared__ char Vim[8192];
  int bid = blockIdx.x, tid = threadIdx.x;
  size_t base = (size_t)bid * (32*128);
  const float* kp = K + base;
  char* ok = wsK + (size_t)bid*8192;
  #pragma unroll
  for (int j = 0; j < 4; ++j){
    int f = tid + j*256; int kr = f>>5, c = f&31;   // kr 0..31, c 0..31
    float4 v = *(const float4*)(kp + kr*128 + c*4);
    unsigned int lo = pack2h(v.x, v.y), hi = pack2h(v.z, v.w);
    int off = kr*256 + ((c*8) ^ ((kr&7)<<4));
    *(uint2*)(ok + off) = make_uint2(lo, hi);
  }
  const float* vp = V + base;
  #pragma unroll
  for (int j = 0; j < 4; ++j){
    int f = tid + j*256; int k = f>>5, c = f&31;    // k 0..31
    float4 v = *(const float4*)(vp + k*128 + c*4);
    float e[4] = {v.x, v.y, v.z, v.w};
    #pragma unroll
    for (int u = 0; u < 4; ++u){
      int d = c*4 + u;
      *(unsigned short*)(Vim + d*64 + ((2*k) ^ ((d&3)<<4))) = f2h16(e[u]);
    }
  }
  __syncthreads();
  char* ov = wsV + (size_t)bid*8192;
  #pragma unroll
  for (int j = 0; j < 2; ++j)
    *(uint4*)(ov + tid*16 + j*4096) = *(const uint4*)(Vim + tid*16 + j*4096);
  if (tid < 128){
    size_t wdx = (size_t)bid*128 + tid;
    const int* p = mask + wdx*32;
    unsigned int o = 0;
    #pragma unroll
    for (int i = 0; i < 32; i += 4){
      int4 m4 = *(const int4*)(p + i);
      o |= (m4.x ? 1u<<i : 0u) | (m4.y ? 1u<<(i+1) : 0u)
         | (m4.z ? 1u<<(i+2) : 0u) | (m4.w ? 1u<<(i+3) : 0u);
    }
    mbits[wdx] = o;
  }
}

// ============ fast attention: KBLK=32, 4 waves x 32 q-rows, 36KB LDS -> 4 blocks/CU
// launch_bounds arg-2 = 2 -> VGPR cap 128 (empirical: cap = 256/arg; arg=4 caused
// a 64-reg cap and catastrophic spill in rounds 10/12). Natural use ~110 <= 128,
// so HW can still co-schedule 4 waves/SIMD; occupancy is then LDS-limited at
// 4 blocks/CU = 16 waves/CU.
__global__ __launch_bounds__(256, 2)
void attn_fast(const float* __restrict__ Q,
               const unsigned int* __restrict__ mbits,
               const char* __restrict__ wsK, const char* __restrict__ wsV,
               float* __restrict__ out)
{
  __shared__ char KB[2][8192];      // K tile: 32 rows x 256B, swz (kr&7)<<4
  __shared__ char VB[2][8192];      // Vt tile: 128 d x 64B, swz (d&3)<<4
  __shared__ char PL[4096];         // 64 q-rows x 64B, swz (r&3)<<4

  int bid = blockIdx.x;
  int wg = (bid & 7) * 128 + (bid >> 3);   // 1024 wgs, bijective XCD swizzle
  int bh = wg >> 4, qb = wg & 15;
  int b  = bh >> 4;
  int tid = threadIdx.x;
  int w = tid >> 6, lane = tid & 63;
  int g = lane >> 4, r = lane & 15;
  int swk = (r & 7) << 4;                  // K-tile swizzle (256B rows)
  int swp = (r & 3) << 4;                  // Vt/PL swizzle (64B rows)
  int sh4 = g * 4;
  size_t base = (size_t)bh * (S_*D_);
  int qg0 = qb*128 + w*32 + r;
  int qg1 = qg0 + 16;
  char* prow = PL + (w*16 + r)*64;

  // precomputed offsets (loop-invariant)
  int xq0 = (g*16) ^ swk;                  // K d-chunk reads (dc*64 strides added)
  int xq1 = (64 + g*16) ^ swk;
  int xq2 = (128 + g*16) ^ swk;
  int xq3 = (192 + g*16) ^ swk;
  int xpt0 = (g*8) ^ swp;                  // PL writes, t=0
  int xpt1 = (32 + g*8) ^ swp;             // t=1
  int xqp = (g*16) ^ swp;                  // PL read / Vt read

  // Q fragments (B-operand of swapped QK^T), 2 q-rows per lane
  f16x8 qf[2][4];
  #pragma unroll
  for (int u = 0; u < 2; ++u){
    const float* qp = Q + base + (size_t)(u ? qg1 : qg0) * D_;
    #pragma unroll
    for (int dc = 0; dc < 4; ++dc){
      float4 a = *(const float4*)(qp + dc*32 + g*8);
      float4 c = *(const float4*)(qp + dc*32 + g*8 + 4);
      f16x8 q8;
      q8[0]=(f16)a.x; q8[1]=(f16)a.y; q8[2]=(f16)a.z; q8[3]=(f16)a.w;
      q8[4]=(f16)c.x; q8[5]=(f16)c.y; q8[6]=(f16)c.z; q8[7]=(f16)c.w;
      qf[u][dc] = q8;
    }
  }

  const char* gK = wsK + (size_t)(bh*64)*8192 + tid*16;
  const char* gV = wsV + (size_t)(bh*64)*8192 + tid*16;
  const unsigned int* mr0 = mbits + ((size_t)b*S_ + qg0)*64;
  const unsigned int* mr1 = mbits + ((size_t)b*S_ + qg1)*64;

  // prologue: masks(0) + stage tile 0 into buffer 0  (FIFO: 2 mask + 4 async)
  unsigned int mwc0 = mr0[0], mwc1 = mr1[0];
  #pragma unroll
  for (int j = 0; j < 2; ++j){
    async16(&KB[0][tid*16 + j*4096], gK + j*4096);
    async16(&VB[0][tid*16 + j*4096], gV + j*4096);
  }

  float m0 = -3.0e38f, m1 = -3.0e38f;
  f32x4 acc[2][8];
  f32x4 accl[2];
  f32x4 z4 = (f32x4){0.f,0.f,0.f,0.f};
  #pragma unroll
  for (int u = 0; u < 2; ++u){
    accl[u] = z4;
    #pragma unroll
    for (int i = 0; i < 8; ++i) acc[u][i] = z4;
  }
  f16x8 ones;
  #pragma unroll
  for (int i = 0; i < 8; ++i) ones[i] = (f16)1.0f;

  unsigned int mwn0 = 0, mwn1 = 0;

  for (int kb = 0; kb < 64; ++kb){
    int cur = kb & 1;
    if (kb < 63){
      mwn0 = mr0[kb+1]; mwn1 = mr1[kb+1];
      const char* gk = gK + (size_t)(kb+1)*8192;
      const char* gv = gV + (size_t)(kb+1)*8192;
      #pragma unroll
      for (int j = 0; j < 2; ++j){
        async16(&KB[cur^1][tid*16 + j*4096], gk + j*4096);
        async16(&VB[cur^1][tid*16 + j*4096], gv + j*4096);
      }
      asm volatile("s_waitcnt vmcnt(6)" ::: "memory");
    } else {
      asm volatile("s_waitcnt vmcnt(0)" ::: "memory");
    }
    __builtin_amdgcn_s_barrier();

    const char* kbuf = KB[cur];
    const char* vbuf = VB[cur];

    // ---- QK^T (swapped), C=0 init via z4 on dc==0 ----
    f32x4 st[2][2];
    __builtin_amdgcn_s_setprio(1);
    #pragma unroll
    for (int t = 0; t < 2; ++t){
      const char* kr_ = kbuf + (t*16 + r)*256;
      f16x8 kf = *(const f16x8*)(kr_ + xq0);
      st[0][t] = __builtin_amdgcn_mfma_f32_16x16x32_f16(kf, qf[0][0], z4, 0, 0, 0);
      st[1][t] = __builtin_amdgcn_mfma_f32_16x16x32_f16(kf, qf[1][0], z4, 0, 0, 0);
      kf = *(const f16x8*)(kr_ + xq1);
      st[0][t] = __builtin_amdgcn_mfma_f32_16x16x32_f16(kf, qf[0][1], st[0][t], 0, 0, 0);
      st[1][t] = __builtin_amdgcn_mfma_f32_16x16x32_f16(kf, qf[1][1], st[1][t], 0, 0, 0);
      kf = *(const f16x8*)(kr_ + xq2);
      st[0][t] = __builtin_amdgcn_mfma_f32_16x16x32_f16(kf, qf[0][2], st[0][t], 0, 0, 0);
      st[1][t] = __builtin_amdgcn_mfma_f32_16x16x32_f16(kf, qf[1][2], st[1][t], 0, 0, 0);
      kf = *(const f16x8*)(kr_ + xq3);
      st[0][t] = __builtin_amdgcn_mfma_f32_16x16x32_f16(kf, qf[0][3], st[0][t], 0, 0, 0);
      st[1][t] = __builtin_amdgcn_mfma_f32_16x16x32_f16(kf, qf[1][3], st[1][t], 0, 0, 0);
    }
    __builtin_amdgcn_s_setprio(0);

    // ---- mask (u32: k = t*16 + g*4 + i) ----
    #pragma unroll
    for (int u = 0; u < 2; ++u){
      unsigned int mw = u ? mwc1 : mwc0;
      unsigned int tv0 = mw >> sh4;
      unsigned int tv1 = mw >> (16 + sh4);
      #pragma unroll
      for (int i = 0; i < 4; ++i){
        if (!((tv0 >> i) & 1u)) st[u][0][i] = NEGV;
        if (!((tv1 >> i) & 1u)) st[u][1][i] = NEGV;
      }
    }

    // ---- online softmax (defer-rescale) ----
    float pmax0 = fmaxf(fmaxf(fmaxf(st[0][0][0], st[0][0][1]), fmaxf(st[0][0][2], st[0][0][3])),
                        fmaxf(fmaxf(st[0][1][0], st[0][1][1]), fmaxf(st[0][1][2], st[0][1][3])));
    float pmax1 = fmaxf(fmaxf(fmaxf(st[1][0][0], st[1][0][1]), fmaxf(st[1][0][2], st[1][0][3])),
                        fmaxf(fmaxf(st[1][1][0], st[1][1][1]), fmaxf(st[1][1][2], st[1][1][3])));
    pmax0 = fmaxf(pmax0, __shfl_xor(pmax0, 16));
    pmax0 = fmaxf(pmax0, __shfl_xor(pmax0, 32));
    pmax1 = fmaxf(pmax1, __shfl_xor(pmax1, 16));
    pmax1 = fmaxf(pmax1, __shfl_xor(pmax1, 32));

    bool need = (pmax0 > m0 + THR) || (pmax1 > m1 + THR);
    if (__ballot(need)){
      float n0 = fmaxf(m0, pmax0), n1 = fmaxf(m1, pmax1);
      float cr0 = __builtin_amdgcn_exp2f((m0 - n0) * LOG2E);
      float cr1 = __builtin_amdgcn_exp2f((m1 - n1) * LOG2E);
      float cj0[4], cj1[4];
      #pragma unroll
      for (int j = 0; j < 4; ++j){
        cj0[j] = __shfl(cr0, sh4 + j);
        cj1[j] = __shfl(cr1, sh4 + j);
      }
      #pragma unroll
      for (int dt = 0; dt < 8; ++dt)
        #pragma unroll
        for (int j = 0; j < 4; ++j){
          acc[0][dt][j] *= cj0[j];
          acc[1][dt][j] *= cj1[j];
        }
      #pragma unroll
      for (int j = 0; j < 4; ++j){
        accl[0][j] *= cj0[j];
        accl[1][j] *= cj1[j];
      }
      m0 = n0; m1 = n1;
    }
    float mL0 = m0 * LOG2E, mL1 = m1 * LOG2E;

    // ---- P = exp2(s*log2e - mL) -> PL -> A-fragments ----
    f16x8 pf[2];
    #pragma unroll
    for (int u = 0; u < 2; ++u){
      float mL = u ? mL1 : mL0;
      {
        float p0 = __builtin_amdgcn_exp2f(__builtin_fmaf(st[u][0][0], LOG2E, -mL));
        float p1 = __builtin_amdgcn_exp2f(__builtin_fmaf(st[u][0][1], LOG2E, -mL));
        float p2 = __builtin_amdgcn_exp2f(__builtin_fmaf(st[u][0][2], LOG2E, -mL));
        float p3 = __builtin_amdgcn_exp2f(__builtin_fmaf(st[u][0][3], LOG2E, -mL));
        *(uint2*)(prow + xpt0) = make_uint2(pkrtz(p0,p1), pkrtz(p2,p3));
        p0 = __builtin_amdgcn_exp2f(__builtin_fmaf(st[u][1][0], LOG2E, -mL));
        p1 = __builtin_amdgcn_exp2f(__builtin_fmaf(st[u][1][1], LOG2E, -mL));
        p2 = __builtin_amdgcn_exp2f(__builtin_fmaf(st[u][1][2], LOG2E, -mL));
        p3 = __builtin_amdgcn_exp2f(__builtin_fmaf(st[u][1][3], LOG2E, -mL));
        *(uint2*)(prow + xpt1) = make_uint2(pkrtz(p0,p1), pkrtz(p2,p3));
      }
      pf[u] = *(const f16x8*)(prow + xqp);
    }

    // ---- row sums via ones-MFMA ----
    accl[0] = __builtin_amdgcn_mfma_f32_16x16x32_f16(pf[0], ones, accl[0], 0, 0, 0);
    accl[1] = __builtin_amdgcn_mfma_f32_16x16x32_f16(pf[1], ones, accl[1], 0, 0, 0);

    // ---- PV: shared V fragments serve both q-halves ----
    __builtin_amdgcn_s_setprio(1);
    #pragma unroll
    for (int dt = 0; dt < 8; ++dt){
      f16x8 v0 = *(const f16x8*)(vbuf + (dt*16 + r)*64 + xqp);
      acc[0][dt] = __builtin_amdgcn_mfma_f32_16x16x32_f16(pf[0], v0, acc[0][dt], 0, 0, 0);
      acc[1][dt] = __builtin_amdgcn_mfma_f32_16x16x32_f16(pf[1], v0, acc[1][dt], 0, 0, 0);
    }
    __builtin_amdgcn_s_setprio(0);

    mwc0 = mwn0; mwc1 = mwn1;
    __builtin_amdgcn_s_barrier();
  }

  // ---- epilogue: normalize by ones-MFMA row sums, store fp32 ----
  #pragma unroll
  for (int u = 0; u < 2; ++u){
    float inv[4];
    #pragma unroll
    for (int j = 0; j < 4; ++j) inv[j] = 1.f / accl[u][j];
    size_t ob = base + (size_t)(qb*128 + w*32 + u*16) * D_;
    #pragma unroll
    for (int dt = 0; dt < 8; ++dt){
      int d = dt*16 + r;
      #pragma unroll
      for (int j = 0; j < 4; ++j)
        out[ob + (size_t)(sh4 + j)*D_ + d] = acc[u][dt][j] * inv[j];
    }
  }
}

// ============ fallback (round-2 proven, direct mask, no ws) ============
constexpr int VTS = 68;
constexpr int PSS = 72;

__global__ __launch_bounds__(256)
void attn_fwd(const float* __restrict__ Q, const float* __restrict__ K,
              const float* __restrict__ V, const int* __restrict__ mask,
              float* __restrict__ out)
{
  __shared__ unsigned short Klds[64 * D_];
  __shared__ unsigned short Vt[D_ * VTS];
  __shared__ unsigned short Plds[4 * 16 * PSS];

  int bid = blockIdx.x;
  int wg = (bid & 7) * 256 + (bid >> 3);
  int bh = wg >> 5, qb = wg & 31;
  int b  = bh >> 4;
  int tid = threadIdx.x;
  int w = tid >> 6, lane = tid & 63;
  int g = lane >> 4, r = lane & 15;
  size_t base = (size_t)bh * S_ * D_;
  int qg = qb * 64 + w * 16 + r;

  f16x8 qf[4];
  {
    const float* qp = Q + base + (size_t)qg * D_;
    #pragma unroll
    for (int dc = 0; dc < 4; ++dc){
      float4 a = *reinterpret_cast<const float4*>(qp + dc*32 + g*8);
      float4 c = *reinterpret_cast<const float4*>(qp + dc*32 + g*8 + 4);
      f16x8 q8;
      q8[0]=(f16)a.x; q8[1]=(f16)a.y; q8[2]=(f16)a.z; q8[3]=(f16)a.w;
      q8[4]=(f16)c.x; q8[5]=(f16)c.y; q8[6]=(f16)c.z; q8[7]=(f16)c.w;
      qf[dc] = q8;
    }
  }

  float mrun = -3.0e38f, lrun = 0.f;
  f32x4 acc[8];
  #pragma unroll
  for (int i = 0; i < 8; ++i) acc[i] = (f32x4){0.f,0.f,0.f,0.f};

  for (int kb = 0; kb < S_/64; ++kb){
    const float* kp = K + base + (size_t)(kb*64) * D_;
    #pragma unroll
    for (int i = 0; i < 8; ++i){
      int f = tid + i*256;
      int kr = f >> 5, c = f & 31;
      float4 v = *reinterpret_cast<const float4*>(kp + kr*D_ + c*4);
      unsigned int lo = pack2h(v.x, v.y), hi = pack2h(v.z, v.w);
      int off = (kr*256 + c*8) ^ ((kr & 7) << 4);
      *reinterpret_cast<uint2*>(reinterpret_cast<char*>(Klds) + off) = make_uint2(lo, hi);
    }
    const float* vp = V + base + (size_t)(kb*64) * D_;
    #pragma unroll
    for (int i = 0; i < 4; ++i){
      int f = tid + i*256;
      int p = f >> 5, c = f & 31;
      float4 v0 = *reinterpret_cast<const float4*>(vp + (size_t)(2*p)*D_ + c*4);
      float4 v1 = *reinterpret_cast<const float4*>(vp + (size_t)(2*p+1)*D_ + c*4);
      float e0[4] = {v0.x, v0.y, v0.z, v0.w};
      float e1[4] = {v1.x, v1.y, v1.z, v1.w};
      #pragma unroll
      for (int j = 0; j < 4; ++j){
        int d = c*4 + j;
        *reinterpret_cast<unsigned int*>(reinterpret_cast<char*>(Vt) + (d*VTS + 2*p)*2)
            = pack2h(e0[j], e1[j]);
      }
    }
    __syncthreads();

    f32x4 st[4];
    #pragma unroll
    for (int t = 0; t < 4; ++t){
      f32x4 s = (f32x4){0.f,0.f,0.f,0.f};
      int row = t*16 + r;
      #pragma unroll
      for (int dc = 0; dc < 4; ++dc){
        int off = row*256 + ((dc*64 + g*16) ^ ((row & 7) << 4));
        f16x8 kf = *reinterpret_cast<const f16x8*>(reinterpret_cast<const char*>(Klds) + off);
        s = __builtin_amdgcn_mfma_f32_16x16x32_f16(kf, qf[dc], s, 0, 0, 0);
      }
      st[t] = s;
    }

    #pragma unroll
    for (int t = 0; t < 4; ++t){
      int4 m4 = *reinterpret_cast<const int4*>(
          mask + ((size_t)b * S_ + qg) * S_ + kb*64 + t*16 + g*4);
      if (!m4.x) st[t][0] = NEGV;
      if (!m4.y) st[t][1] = NEGV;
      if (!m4.z) st[t][2] = NEGV;
      if (!m4.w) st[t][3] = NEGV;
    }

    float pmax = st[0][0];
    #pragma unroll
    for (int t = 0; t < 4; ++t)
      #pragma unroll
      for (int i = 0; i < 4; ++i) pmax = fmaxf(pmax, st[t][i]);
    pmax = fmaxf(pmax, __shfl_xor(pmax, 16));
    pmax = fmaxf(pmax, __shfl_xor(pmax, 32));
    float mnew = fmaxf(mrun, pmax);
    float corr = __builtin_amdgcn_exp2f((mrun - mnew) * LOG2E);
    float psum = 0.f;
    char* prow = reinterpret_cast<char*>(Plds) + (size_t)(w*16 + r)*PSS*2;
    #pragma unroll
    for (int t = 0; t < 4; ++t){
      float p0 = __builtin_amdgcn_exp2f((st[t][0]-mnew)*LOG2E);
      float p1 = __builtin_amdgcn_exp2f((st[t][1]-mnew)*LOG2E);
      float p2 = __builtin_amdgcn_exp2f((st[t][2]-mnew)*LOG2E);
      float p3 = __builtin_amdgcn_exp2f((st[t][3]-mnew)*LOG2E);
      psum += (p0+p1)+(p2+p3);
      char* pb = prow + (t*16 + g*4)*2;
      *reinterpret_cast<unsigned int*>(pb)     = pack2h(p0, p1);
      *reinterpret_cast<unsigned int*>(pb + 4) = pack2h(p2, p3);
    }
    psum += __shfl_xor(psum, 16);
    psum += __shfl_xor(psum, 32);
    lrun = lrun * corr + psum;
    mrun = mnew;
    float cq0 = __shfl(corr, g*4 + 0);
    float cq1 = __shfl(corr, g*4 + 1);
    float cq2 = __shfl(corr, g*4 + 2);
    float cq3 = __shfl(corr, g*4 + 3);
    #pragma unroll
    for (int dt = 0; dt < 8; ++dt){
      acc[dt][0] *= cq0; acc[dt][1] *= cq1; acc[dt][2] *= cq2; acc[dt][3] *= cq3;
    }

    f16x8 pf0 = *reinterpret_cast<const f16x8*>(prow + g*16);
    f16x8 pf1 = *reinterpret_cast<const f16x8*>(prow + 64 + g*16);
    #pragma unroll
    for (int dt = 0; dt < 8; ++dt){
      int vo = (dt*16 + r)*VTS*2 + g*16;
      const char* vb = reinterpret_cast<const char*>(Vt);
      union { f16x8 v; f16x4v h[2]; } uv0, uv1;
      uv0.h[0] = *reinterpret_cast<const f16x4v*>(vb + vo);
      uv0.h[1] = *reinterpret_cast<const f16x4v*>(vb + vo + 8);
      acc[dt] = __builtin_amdgcn_mfma_f32_16x16x32_f16(pf0, uv0.v, acc[dt], 0, 0, 0);
      uv1.h[0] = *reinterpret_cast<const f16x4v*>(vb + vo + 64);
      uv1.h[1] = *reinterpret_cast<const f16x4v*>(vb + vo + 72);
      acc[dt] = __builtin_amdgcn_mfma_f32_16x16x32_f16(pf1, uv1.v, acc[dt], 0, 0, 0);
    }
    __syncthreads();
  }

  float l0 = __shfl(lrun, g*4 + 0);
  float l1 = __shfl(lrun, g*4 + 1);
  float l2 = __shfl(lrun, g*4 + 2);
  float l3 = __shfl(lrun, g*4 + 3);
  float i0 = 1.f/l0, i1 = 1.f/l1, i2 = 1.f/l2, i3 = 1.f/l3;
  size_t obase = base + (size_t)(qb*64 + w*16) * D_;
  #pragma unroll
  for (int dt = 0; dt < 8; ++dt){
    int d = dt*16 + r;
    out[obase + (size_t)(g*4 + 0)*D_ + d] = acc[dt][0]*i0;
    out[obase + (size_t)(g*4 + 1)*D_ + d] = acc[dt][1]*i1;
    out[obase + (size_t)(g*4 + 2)*D_ + d] = acc[dt][2]*i2;
    out[obase + (size_t)(g*4 + 3)*D_ + d] = acc[dt][3]*i3;
  }
}

extern "C" void kernel_launch(void* const* d_in, const int* in_sizes, int n_in,
                              void* d_out, int out_size, void* d_ws, size_t ws_size,
                              hipStream_t stream) {
  const float* Q = (const float*)d_in[0];
  const float* K = (const float*)d_in[1];
  const float* V = (const float*)d_in[2];
  const int* mask = (const int*)d_in[3];
  float* out = (float*)d_out;

  if (ws_size >= WS_MID){
    unsigned int* mbits = (unsigned int*)d_ws;
    char* wsK = (char*)d_ws + MBW*4;
    char* wsV = wsK + KBYTES;
    prepass<<<dim3(4096), dim3(256), 0, stream>>>(K, V, mask, mbits, wsK, wsV);
    attn_fast<<<dim3(1024), dim3(256), 0, stream>>>(Q, mbits, wsK, wsV, out);
  } else {
    attn_fwd<<<dim3(2048), dim3(256), 0, stream>>>(Q, K, V, mask, out);
  }
}

// Round 14
// 247.419 us; speedup vs baseline: 3.0200x; 1.1811x over previous
//
#include <hip/hip_runtime.h>
#include <hip/hip_bf16.h>

#define B_ 4
#define H_ 16
#define S_ 2048
#define D_ 128
#define NEGV -1000000000.0f
#define LOG2E 1.44269504f
#define THR 9.0f

typedef _Float16 f16;
typedef __attribute__((ext_vector_type(8))) _Float16 f16x8;
typedef __attribute__((ext_vector_type(4))) _Float16 f16x4v;
typedef __attribute__((ext_vector_type(2))) __fp16 fp16x2_b;
typedef __attribute__((ext_vector_type(4))) float f32x4;

__device__ inline unsigned int pack2h(float lo, float hi){
  union { f16 h[2]; unsigned int u; } cv;
  cv.h[0] = (f16)lo; cv.h[1] = (f16)hi;
  return cv.u;
}
__device__ inline unsigned short f2h16(float x){
  union { f16 h; unsigned short u; } cv; cv.h = (f16)x; return cv.u;
}
__device__ inline unsigned int pkrtz(float a, float b){
  union { fp16x2_b h; unsigned int u; } cv;
  cv.h = __builtin_amdgcn_cvt_pkrtz(a, b);
  return cv.u;
}
__device__ inline void async16(void* l, const void* g){
  __builtin_amdgcn_global_load_lds(
      (const __attribute__((address_space(1))) unsigned int*)g,
      (__attribute__((address_space(3))) unsigned int*)l, 16, 0, 0);
}

// ws layout (MID): [mask bits 2MB][K f16 tiles 32MB][Vt f16 tiles 32MB]
constexpr size_t MBW     = (size_t)B_*S_*(S_/32);       // 524288 words
constexpr size_t KBYTES  = (size_t)B_*H_*S_*D_*2;       // 33554432
constexpr size_t WS_MID  = MBW*4 + 2*KBYTES;            // 69206016

// ============ prepass: K->f16 swizzled tiles, V->f16 transposed swizzled tiles, mask->bits
__global__ __launch_bounds__(256)
void prepass(const float* __restrict__ K, const float* __restrict__ V,
             const int* __restrict__ mask, unsigned int* __restrict__ mbits,
             char* __restrict__ wsK, char* __restrict__ wsV)
{
  __shared__ char Vim[16384];
  int bid = blockIdx.x, tid = threadIdx.x;     // bid = bh*32 + kb
  size_t base = (size_t)bid * (64*128);
  const float* kp = K + base;
  char* ok = wsK + (size_t)bid*16384;
  #pragma unroll
  for (int j = 0; j < 8; ++j){
    int f = tid + j*256; int kr = f>>5, c = f&31;
    float4 v = *(const float4*)(kp + kr*128 + c*4);
    unsigned int lo = pack2h(v.x, v.y), hi = pack2h(v.z, v.w);
    int off = (kr*256 + c*8) ^ ((kr&7)<<4);
    *(uint2*)(ok + off) = make_uint2(lo, hi);
  }
  const float* vp = V + base;
  #pragma unroll
  for (int j = 0; j < 8; ++j){
    int f = tid + j*256; int k = f>>5, c = f&31;
    float4 v = *(const float4*)(vp + k*128 + c*4);
    float e[4] = {v.x, v.y, v.z, v.w};
    #pragma unroll
    for (int u = 0; u < 4; ++u){
      int d = c*4 + u;
      *(unsigned short*)(Vim + d*128 + ((2*k) ^ ((d&7)<<4))) = f2h16(e[u]);
    }
  }
  __syncthreads();
  char* ov = wsV + (size_t)bid*16384;
  #pragma unroll
  for (int j = 0; j < 4; ++j)
    *(uint4*)(ov + tid*16 + j*4096) = *(const uint4*)(Vim + tid*16 + j*4096);
  {
    size_t wdx = (size_t)bid*256 + tid;
    const int* p = mask + wdx*32;
    unsigned int o = 0;
    #pragma unroll
    for (int i = 0; i < 32; i += 4){
      int4 m4 = *(const int4*)(p + i);
      o |= (m4.x ? 1u<<i : 0u) | (m4.y ? 1u<<(i+1) : 0u)
         | (m4.z ? 1u<<(i+2) : 0u) | (m4.w ? 1u<<(i+3) : 0u);
    }
    mbits[wdx] = o;
  }
}

// ============ fast attention: round-8/9 proven structure (best measured: 226.6 us) ====
// One iteration: stage tile KB+1 into (KS,VS); vmcnt(10) drains prev iter's loads;
// barrier; QK^T from (KC,VC) with C=0 init; mask+softmax (defer-rescale);
// P->PL->A-frags; ones-MFMA row sums; PV; barrier.
#define ITER(KB, KC, VC, KS, VS, MWI0, MWI1, MWO0, MWO1, LAST)                 \
  do {                                                                         \
    if (!(LAST)){                                                              \
      MWO0 = mr0[(KB)+1];  MWO1 = mr1[(KB)+1];                                 \
      const char* gk_ = gK + (size_t)((KB)+1)*16384;                           \
      const char* gv_ = gV + (size_t)((KB)+1)*16384;                           \
      _Pragma("unroll")                                                        \
      for (int j = 0; j < 4; ++j){                                             \
        async16((KS) + tid*16 + j*4096, gk_ + j*4096);                         \
        async16((VS) + tid*16 + j*4096, gv_ + j*4096);                         \
      }                                                                        \
      asm volatile("s_waitcnt vmcnt(10)" ::: "memory");                        \
    } else {                                                                   \
      asm volatile("s_waitcnt vmcnt(0)" ::: "memory");                         \
    }                                                                          \
    __builtin_amdgcn_s_barrier();                                              \
    f32x4 st0[4], st1[4];                                                      \
    __builtin_amdgcn_s_setprio(1);                                             \
    _Pragma("unroll")                                                          \
    for (int t = 0; t < 4; ++t){                                               \
      const char* kr_ = (KC) + r256 + t*4096;                                  \
      f16x8 kf = *(const f16x8*)(kr_ + xq0);                                   \
      st0[t] = __builtin_amdgcn_mfma_f32_16x16x32_f16(kf, qf[0][0], z4, 0,0,0);\
      st1[t] = __builtin_amdgcn_mfma_f32_16x16x32_f16(kf, qf[1][0], z4, 0,0,0);\
      kf = *(const f16x8*)(kr_ + xq1);                                         \
      st0[t] = __builtin_amdgcn_mfma_f32_16x16x32_f16(kf, qf[0][1], st0[t],0,0,0);\
      st1[t] = __builtin_amdgcn_mfma_f32_16x16x32_f16(kf, qf[1][1], st1[t],0,0,0);\
      kf = *(const f16x8*)(kr_ + xq2);                                         \
      st0[t] = __builtin_amdgcn_mfma_f32_16x16x32_f16(kf, qf[0][2], st0[t],0,0,0);\
      st1[t] = __builtin_amdgcn_mfma_f32_16x16x32_f16(kf, qf[1][2], st1[t],0,0,0);\
      kf = *(const f16x8*)(kr_ + xq3);                                         \
      st0[t] = __builtin_amdgcn_mfma_f32_16x16x32_f16(kf, qf[0][3], st0[t],0,0,0);\
      st1[t] = __builtin_amdgcn_mfma_f32_16x16x32_f16(kf, qf[1][3], st1[t],0,0,0);\
    }                                                                          \
    __builtin_amdgcn_s_setprio(0);                                             \
    /* mask (bits): per 16-row half, compile-time bit positions */             \
    {                                                                          \
      unsigned int mlo = (unsigned int)((MWI0) >> sh4);                        \
      unsigned int mhi = (unsigned int)((MWI0) >> (sh4 + 32));                 \
      _Pragma("unroll")                                                        \
      for (int t = 0; t < 4; ++t){                                             \
        unsigned int tv = (t & 2) ? mhi : mlo;                                 \
        _Pragma("unroll")                                                      \
        for (int i = 0; i < 4; ++i)                                            \
          if (!((tv >> (((t&1)*16) + i)) & 1u)) st0[t][i] = NEGV;              \
      }                                                                        \
      mlo = (unsigned int)((MWI1) >> sh4);                                     \
      mhi = (unsigned int)((MWI1) >> (sh4 + 32));                              \
      _Pragma("unroll")                                                        \
      for (int t = 0; t < 4; ++t){                                             \
        unsigned int tv = (t & 2) ? mhi : mlo;                                 \
        _Pragma("unroll")                                                      \
        for (int i = 0; i < 4; ++i)                                            \
          if (!((tv >> (((t&1)*16) + i)) & 1u)) st1[t][i] = NEGV;              \
      }                                                                        \
    }                                                                          \
    /* tree max per u */                                                       \
    float q00 = fmaxf(fmaxf(st0[0][0], st0[0][1]), fmaxf(st0[0][2], st0[0][3]));\
    float q01 = fmaxf(fmaxf(st0[1][0], st0[1][1]), fmaxf(st0[1][2], st0[1][3]));\
    float q02 = fmaxf(fmaxf(st0[2][0], st0[2][1]), fmaxf(st0[2][2], st0[2][3]));\
    float q03 = fmaxf(fmaxf(st0[3][0], st0[3][1]), fmaxf(st0[3][2], st0[3][3]));\
    float pmax0 = fmaxf(fmaxf(q00, q01), fmaxf(q02, q03));                     \
    float q10 = fmaxf(fmaxf(st1[0][0], st1[0][1]), fmaxf(st1[0][2], st1[0][3]));\
    float q11 = fmaxf(fmaxf(st1[1][0], st1[1][1]), fmaxf(st1[1][2], st1[1][3]));\
    float q12 = fmaxf(fmaxf(st1[2][0], st1[2][1]), fmaxf(st1[2][2], st1[2][3]));\
    float q13 = fmaxf(fmaxf(st1[3][0], st1[3][1]), fmaxf(st1[3][2], st1[3][3]));\
    float pmax1 = fmaxf(fmaxf(q10, q11), fmaxf(q12, q13));                     \
    pmax0 = fmaxf(pmax0, __shfl_xor(pmax0, 16));                               \
    pmax0 = fmaxf(pmax0, __shfl_xor(pmax0, 32));                               \
    pmax1 = fmaxf(pmax1, __shfl_xor(pmax1, 16));                               \
    pmax1 = fmaxf(pmax1, __shfl_xor(pmax1, 32));                               \
    bool need = (pmax0 > m0 + THR) || (pmax1 > m1 + THR);                      \
    if (__ballot(need)){                                                       \
      float n0 = fmaxf(m0, pmax0), n1 = fmaxf(m1, pmax1);                      \
      float cr0 = __builtin_amdgcn_exp2f((m0 - n0) * LOG2E);                   \
      float cr1 = __builtin_amdgcn_exp2f((m1 - n1) * LOG2E);                   \
      float cj0[4], cj1[4];                                                    \
      _Pragma("unroll")                                                        \
      for (int j = 0; j < 4; ++j){                                             \
        cj0[j] = __shfl(cr0, sh4 + j);                                         \
        cj1[j] = __shfl(cr1, sh4 + j);                                         \
      }                                                                        \
      _Pragma("unroll")                                                        \
      for (int dt = 0; dt < 8; ++dt)                                           \
        _Pragma("unroll")                                                      \
        for (int j = 0; j < 4; ++j){                                           \
          acc[0][dt][j] *= cj0[j];                                             \
          acc[1][dt][j] *= cj1[j];                                             \
        }                                                                      \
      _Pragma("unroll")                                                        \
      for (int j = 0; j < 4; ++j){                                             \
        accl[0][j] *= cj0[j];                                                  \
        accl[1][j] *= cj1[j];                                                  \
      }                                                                        \
      m0 = n0; m1 = n1;                                                        \
    }                                                                          \
    float mL0 = m0 * LOG2E, mL1 = m1 * LOG2E;                                  \
    f16x8 pf00, pf01, pf10, pf11;                                              \
    {                                                                          \
      _Pragma("unroll")                                                        \
      for (int t = 0; t < 4; ++t){                                             \
        float p0 = __builtin_amdgcn_exp2f(__builtin_fmaf(st0[t][0], LOG2E, -mL0));\
        float p1 = __builtin_amdgcn_exp2f(__builtin_fmaf(st0[t][1], LOG2E, -mL0));\
        float p2 = __builtin_amdgcn_exp2f(__builtin_fmaf(st0[t][2], LOG2E, -mL0));\
        float p3 = __builtin_amdgcn_exp2f(__builtin_fmaf(st0[t][3], LOG2E, -mL0));\
        *(uint2*)(prow + xpt[t]) = make_uint2(pkrtz(p0,p1), pkrtz(p2,p3));     \
      }                                                                        \
      pf00 = *(const f16x8*)(prow + xq0p);                                     \
      pf01 = *(const f16x8*)(prow + xq1p);                                     \
      _Pragma("unroll")                                                        \
      for (int t = 0; t < 4; ++t){                                             \
        float p0 = __builtin_amdgcn_exp2f(__builtin_fmaf(st1[t][0], LOG2E, -mL1));\
        float p1 = __builtin_amdgcn_exp2f(__builtin_fmaf(st1[t][1], LOG2E, -mL1));\
        float p2 = __builtin_amdgcn_exp2f(__builtin_fmaf(st1[t][2], LOG2E, -mL1));\
        float p3 = __builtin_amdgcn_exp2f(__builtin_fmaf(st1[t][3], LOG2E, -mL1));\
        *(uint2*)(prow + xpt[t]) = make_uint2(pkrtz(p0,p1), pkrtz(p2,p3));     \
      }                                                                        \
      pf10 = *(const f16x8*)(prow + xq0p);                                     \
      pf11 = *(const f16x8*)(prow + xq1p);                                     \
    }                                                                          \
    accl[0] = __builtin_amdgcn_mfma_f32_16x16x32_f16(pf00, ones, accl[0], 0,0,0);\
    accl[0] = __builtin_amdgcn_mfma_f32_16x16x32_f16(pf01, ones, accl[0], 0,0,0);\
    accl[1] = __builtin_amdgcn_mfma_f32_16x16x32_f16(pf10, ones, accl[1], 0,0,0);\
    accl[1] = __builtin_amdgcn_mfma_f32_16x16x32_f16(pf11, ones, accl[1], 0,0,0);\
    __builtin_amdgcn_s_setprio(1);                                             \
    _Pragma("unroll")                                                          \
    for (int dt = 0; dt < 8; ++dt){                                            \
      const char* vr_ = (VC) + r128 + dt*2048;                                 \
      f16x8 v0 = *(const f16x8*)(vr_ + xq0p);                                  \
      f16x8 v1 = *(const f16x8*)(vr_ + xq1p);                                  \
      acc[0][dt] = __builtin_amdgcn_mfma_f32_16x16x32_f16(pf00, v0, acc[0][dt], 0,0,0);\
      acc[0][dt] = __builtin_amdgcn_mfma_f32_16x16x32_f16(pf01, v1, acc[0][dt], 0,0,0);\
      acc[1][dt] = __builtin_amdgcn_mfma_f32_16x16x32_f16(pf10, v0, acc[1][dt], 0,0,0);\
      acc[1][dt] = __builtin_amdgcn_mfma_f32_16x16x32_f16(pf11, v1, acc[1][dt], 0,0,0);\
    }                                                                          \
    __builtin_amdgcn_s_setprio(0);                                             \
    __builtin_amdgcn_s_barrier();                                              \
  } while(0)

__global__ __launch_bounds__(256, 2)
void attn_fast(const float* __restrict__ Q,
               const unsigned long long* __restrict__ mbits,
               const char* __restrict__ wsK, const char* __restrict__ wsV,
               float* __restrict__ out)
{
  __shared__ char KB0[16384];
  __shared__ char KB1[16384];
  __shared__ char VB0[16384];
  __shared__ char VB1[16384];
  __shared__ char PL[8192];

  int bid = blockIdx.x;
  int wg = (bid & 7) * 128 + (bid >> 3);   // 1024 wgs, bijective XCD swizzle
  int bh = wg >> 4, qb = wg & 15;
  int b  = bh >> 4;
  int tid = threadIdx.x;
  int w = tid >> 6, lane = tid & 63;
  int g = lane >> 4, r = lane & 15;
  int sw = (r & 7) << 4;
  int sh4 = g * 4;
  size_t base = (size_t)bh * (S_*D_);
  int qg0 = qb*128 + w*32 + r;
  int qg1 = qg0 + 16;
  char* prow = PL + (w*16 + r)*128;

  // precomputed swizzled offsets (loop-invariant)
  int r256 = r*256, r128 = r*128;
  int xq0 = (g*16) ^ sw;
  int xq1 = (64 + g*16) ^ sw;
  int xq2 = (128 + g*16) ^ sw;
  int xq3 = (192 + g*16) ^ sw;
  int xq0p = xq0, xq1p = xq1;              // PL/V reads use same pattern
  int xpt[4];
  #pragma unroll
  for (int t = 0; t < 4; ++t) xpt[t] = (t*32 + g*8) ^ sw;

  // Q fragments (B-operand of swapped QK^T), 2 q-rows per lane
  f16x8 qf[2][4];
  #pragma unroll
  for (int u = 0; u < 2; ++u){
    const float* qp = Q + base + (size_t)(u ? qg1 : qg0) * D_;
    #pragma unroll
    for (int dc = 0; dc < 4; ++dc){
      float4 a = *(const float4*)(qp + dc*32 + g*8);
      float4 c = *(const float4*)(qp + dc*32 + g*8 + 4);
      f16x8 q8;
      q8[0]=(f16)a.x; q8[1]=(f16)a.y; q8[2]=(f16)a.z; q8[3]=(f16)a.w;
      q8[4]=(f16)c.x; q8[5]=(f16)c.y; q8[6]=(f16)c.z; q8[7]=(f16)c.w;
      qf[u][dc] = q8;
    }
  }

  const char* gK = wsK + (size_t)(bh*32)*16384 + tid*16;
  const char* gV = wsV + (size_t)(bh*32)*16384 + tid*16;
  const unsigned long long* mr0 = mbits + ((size_t)b*S_ + qg0)*32;
  const unsigned long long* mr1 = mbits + ((size_t)b*S_ + qg1)*32;

  // prologue: masks(0) + stage tile 0 into buffer 0
  unsigned long long mwA0 = mr0[0], mwA1 = mr1[0];
  unsigned long long mwB0 = 0, mwB1 = 0;
  #pragma unroll
  for (int j = 0; j < 4; ++j){
    async16(KB0 + tid*16 + j*4096, gK + j*4096);
    async16(VB0 + tid*16 + j*4096, gV + j*4096);
  }

  float m0 = -3.0e38f, m1 = -3.0e38f;
  f32x4 acc[2][8];
  f32x4 accl[2];
  f32x4 z4 = (f32x4){0.f,0.f,0.f,0.f};
  #pragma unroll
  for (int u = 0; u < 2; ++u){
    accl[u] = z4;
    #pragma unroll
    for (int i = 0; i < 8; ++i) acc[u][i] = z4;
  }
  f16x8 ones;
  #pragma unroll
  for (int i = 0; i < 8; ++i) ones[i] = (f16)1.0f;

  // main loop: 32 iters, unrolled by 2 with static buffers + ping-pong masks
  for (int kb2 = 0; kb2 < 32; kb2 += 2){
    ITER(kb2,   KB0, VB0, KB1, VB1, mwA0, mwA1, mwB0, mwB1, false);
    ITER(kb2+1, KB1, VB1, KB0, VB0, mwB0, mwB1, mwA0, mwA1, (kb2 == 30));
  }

  // ---- epilogue: normalize by ones-MFMA row sums, store fp32 ----
  #pragma unroll
  for (int u = 0; u < 2; ++u){
    float inv[4];
    #pragma unroll
    for (int j = 0; j < 4; ++j) inv[j] = 1.f / accl[u][j];
    size_t ob = base + (size_t)(qb*128 + w*32 + u*16) * D_;
    #pragma unroll
    for (int dt = 0; dt < 8; ++dt){
      int d = dt*16 + r;
      #pragma unroll
      for (int j = 0; j < 4; ++j)
        out[ob + (size_t)(sh4 + j)*D_ + d] = acc[u][dt][j] * inv[j];
    }
  }
}

// ============ fallback (round-2 proven, direct mask, no ws) ============
constexpr int VTS = 68;
constexpr int PSS = 72;

__global__ __launch_bounds__(256)
void attn_fwd(const float* __restrict__ Q, const float* __restrict__ K,
              const float* __restrict__ V, const int* __restrict__ mask,
              float* __restrict__ out)
{
  __shared__ unsigned short Klds[64 * D_];
  __shared__ unsigned short Vt[D_ * VTS];
  __shared__ unsigned short Plds[4 * 16 * PSS];

  int bid = blockIdx.x;
  int wg = (bid & 7) * 256 + (bid >> 3);
  int bh = wg >> 5, qb = wg & 31;
  int b  = bh >> 4;
  int tid = threadIdx.x;
  int w = tid >> 6, lane = tid & 63;
  int g = lane >> 4, r = lane & 15;
  size_t base = (size_t)bh * S_ * D_;
  int qg = qb * 64 + w * 16 + r;

  f16x8 qf[4];
  {
    const float* qp = Q + base + (size_t)qg * D_;
    #pragma unroll
    for (int dc = 0; dc < 4; ++dc){
      float4 a = *reinterpret_cast<const float4*>(qp + dc*32 + g*8);
      float4 c = *reinterpret_cast<const float4*>(qp + dc*32 + g*8 + 4);
      f16x8 q8;
      q8[0]=(f16)a.x; q8[1]=(f16)a.y; q8[2]=(f16)a.z; q8[3]=(f16)a.w;
      q8[4]=(f16)c.x; q8[5]=(f16)c.y; q8[6]=(f16)c.z; q8[7]=(f16)c.w;
      qf[dc] = q8;
    }
  }

  float mrun = -3.0e38f, lrun = 0.f;
  f32x4 acc[8];
  #pragma unroll
  for (int i = 0; i < 8; ++i) acc[i] = (f32x4){0.f,0.f,0.f,0.f};

  for (int kb = 0; kb < S_/64; ++kb){
    const float* kp = K + base + (size_t)(kb*64) * D_;
    #pragma unroll
    for (int i = 0; i < 8; ++i){
      int f = tid + i*256;
      int kr = f >> 5, c = f & 31;
      float4 v = *reinterpret_cast<const float4*>(kp + kr*D_ + c*4);
      unsigned int lo = pack2h(v.x, v.y), hi = pack2h(v.z, v.w);
      int off = (kr*256 + c*8) ^ ((kr & 7) << 4);
      *reinterpret_cast<uint2*>(reinterpret_cast<char*>(Klds) + off) = make_uint2(lo, hi);
    }
    const float* vp = V + base + (size_t)(kb*64) * D_;
    #pragma unroll
    for (int i = 0; i < 4; ++i){
      int f = tid + i*256;
      int p = f >> 5, c = f & 31;
      float4 v0 = *reinterpret_cast<const float4*>(vp + (size_t)(2*p)*D_ + c*4);
      float4 v1 = *reinterpret_cast<const float4*>(vp + (size_t)(2*p+1)*D_ + c*4);
      float e0[4] = {v0.x, v0.y, v0.z, v0.w};
      float e1[4] = {v1.x, v1.y, v1.z, v1.w};
      #pragma unroll
      for (int j = 0; j < 4; ++j){
        int d = c*4 + j;
        *reinterpret_cast<unsigned int*>(reinterpret_cast<char*>(Vt) + (d*VTS + 2*p)*2)
            = pack2h(e0[j], e1[j]);
      }
    }
    __syncthreads();

    f32x4 st[4];
    #pragma unroll
    for (int t = 0; t < 4; ++t){
      f32x4 s = (f32x4){0.f,0.f,0.f,0.f};
      int row = t*16 + r;
      #pragma unroll
      for (int dc = 0; dc < 4; ++dc){
        int off = row*256 + ((dc*64 + g*16) ^ ((row & 7) << 4));
        f16x8 kf = *reinterpret_cast<const f16x8*>(reinterpret_cast<const char*>(Klds) + off);
        s = __builtin_amdgcn_mfma_f32_16x16x32_f16(kf, qf[dc], s, 0, 0, 0);
      }
      st[t] = s;
    }

    #pragma unroll
    for (int t = 0; t < 4; ++t){
      int4 m4 = *reinterpret_cast<const int4*>(
          mask + ((size_t)b * S_ + qg) * S_ + kb*64 + t*16 + g*4);
      if (!m4.x) st[t][0] = NEGV;
      if (!m4.y) st[t][1] = NEGV;
      if (!m4.z) st[t][2] = NEGV;
      if (!m4.w) st[t][3] = NEGV;
    }

    float pmax = st[0][0];
    #pragma unroll
    for (int t = 0; t < 4; ++t)
      #pragma unroll
      for (int i = 0; i < 4; ++i) pmax = fmaxf(pmax, st[t][i]);
    pmax = fmaxf(pmax, __shfl_xor(pmax, 16));
    pmax = fmaxf(pmax, __shfl_xor(pmax, 32));
    float mnew = fmaxf(mrun, pmax);
    float corr = __builtin_amdgcn_exp2f((mrun - mnew) * LOG2E);
    float psum = 0.f;
    char* prow = reinterpret_cast<char*>(Plds) + (size_t)(w*16 + r)*PSS*2;
    #pragma unroll
    for (int t = 0; t < 4; ++t){
      float p0 = __builtin_amdgcn_exp2f((st[t][0]-mnew)*LOG2E);
      float p1 = __builtin_amdgcn_exp2f((st[t][1]-mnew)*LOG2E);
      float p2 = __builtin_amdgcn_exp2f((st[t][2]-mnew)*LOG2E);
      float p3 = __builtin_amdgcn_exp2f((st[t][3]-mnew)*LOG2E);
      psum += (p0+p1)+(p2+p3);
      char* pb = prow + (t*16 + g*4)*2;
      *reinterpret_cast<unsigned int*>(pb)     = pack2h(p0, p1);
      *reinterpret_cast<unsigned int*>(pb + 4) = pack2h(p2, p3);
    }
    psum += __shfl_xor(psum, 16);
    psum += __shfl_xor(psum, 32);
    lrun = lrun * corr + psum;
    mrun = mnew;
    float cq0 = __shfl(corr, g*4 + 0);
    float cq1 = __shfl(corr, g*4 + 1);
    float cq2 = __shfl(corr, g*4 + 2);
    float cq3 = __shfl(corr, g*4 + 3);
    #pragma unroll
    for (int dt = 0; dt < 8; ++dt){
      acc[dt][0] *= cq0; acc[dt][1] *= cq1; acc[dt][2] *= cq2; acc[dt][3] *= cq3;
    }

    f16x8 pf0 = *reinterpret_cast<const f16x8*>(prow + g*16);
    f16x8 pf1 = *reinterpret_cast<const f16x8*>(prow + 64 + g*16);
    #pragma unroll
    for (int dt = 0; dt < 8; ++dt){
      int vo = (dt*16 + r)*VTS*2 + g*16;
      const char* vb = reinterpret_cast<const char*>(Vt);
      union { f16x8 v; f16x4v h[2]; } uv0, uv1;
      uv0.h[0] = *reinterpret_cast<const f16x4v*>(vb + vo);
      uv0.h[1] = *reinterpret_cast<const f16x4v*>(vb + vo + 8);
      acc[dt] = __builtin_amdgcn_mfma_f32_16x16x32_f16(pf0, uv0.v, acc[dt], 0, 0, 0);
      uv1.h[0] = *reinterpret_cast<const f16x4v*>(vb + vo + 64);
      uv1.h[1] = *reinterpret_cast<const f16x4v*>(vb + vo + 72);
      acc[dt] = __builtin_amdgcn_mfma_f32_16x16x32_f16(pf1, uv1.v, acc[dt], 0, 0, 0);
    }
    __syncthreads();
  }

  float l0 = __shfl(lrun, g*4 + 0);
  float l1 = __shfl(lrun, g*4 + 1);
  float l2 = __shfl(lrun, g*4 + 2);
  float l3 = __shfl(lrun, g*4 + 3);
  float i0 = 1.f/l0, i1 = 1.f/l1, i2 = 1.f/l2, i3 = 1.f/l3;
  size_t obase = base + (size_t)(qb*64 + w*16) * D_;
  #pragma unroll
  for (int dt = 0; dt < 8; ++dt){
    int d = dt*16 + r;
    out[obase + (size_t)(g*4 + 0)*D_ + d] = acc[dt][0]*i0;
    out[obase + (size_t)(g*4 + 1)*D_ + d] = acc[dt][1]*i1;
    out[obase + (size_t)(g*4 + 2)*D_ + d] = acc[dt][2]*i2;
    out[obase + (size_t)(g*4 + 3)*D_ + d] = acc[dt][3]*i3;
  }
}

extern "C" void kernel_launch(void* const* d_in, const int* in_sizes, int n_in,
                              void* d_out, int out_size, void* d_ws, size_t ws_size,
                              hipStream_t stream) {
  const float* Q = (const float*)d_in[0];
  const float* K = (const float*)d_in[1];
  const float* V = (const float*)d_in[2];
  const int* mask = (const int*)d_in[3];
  float* out = (float*)d_out;
  dim3 blk(256);

  if (ws_size >= WS_MID){
    unsigned int* mbits = (unsigned int*)d_ws;
    char* wsK = (char*)d_ws + MBW*4;
    char* wsV = wsK + KBYTES;
    prepass<<<dim3(2048), blk, 0, stream>>>(K, V, mask, mbits, wsK, wsV);
    attn_fast<<<dim3(1024), blk, 0, stream>>>(Q, (const unsigned long long*)d_ws,
                                              wsK, wsV, out);
  } else {
    attn_fwd<<<dim3(2048), blk, 0, stream>>>(Q, K, V, mask, out);
  }
}